// Round 9
// baseline (200.801 us; speedup 1.0000x reference)
//
#include <hip/hip_runtime.h>
#include <math.h>

// CTC forward loss, linear-domain alpha recursion with power-of-2 renorm.
// Round-9: producer/consumer. R7 and R8 both measured ~148 cy/step with
// totally different memory structures -> common wall is the per-WAVE cache-
// line fetch rate (~18 cy/line; each row needs ~8 lines). One wave can't go
// faster. So: 4 producer waves gather the 3 needed dwords/row into an LDS
// ring (SoA, conflict-free), wave 0 runs the serial recursion LDS-only.
// Workgroup-scope acquire/release flags; monotonic, deadlock-free.
// Numerics identical to R7/R8 (commit p+eps, 2^40-recenter renorm) -> same
// absmax (~64).

#define T_DIM 1024
#define C_DIM 128
#define U_DIM 128
#define EPSF  1e-7f
#define LN2F  0.6931471805599453f
#define TARGET_BEXP 294        // 0x126: recenter wave max at 2^40
#define NPROD  4
#define GROUP_ROWS 16
#define GROUPS (T_DIM / GROUP_ROWS)   // 64
#define RING 4

__device__ __forceinline__ float dpp_wave_shr1(float x) {
  // wave_shr:1; old=0, bound_ctrl=false -> lane 0 reads exact 0.0f
  return __int_as_float(__builtin_amdgcn_update_dpp(
      0, __float_as_int(x), 0x138, 0xf, 0xf, false));
}
#define ROR_MAX(red, CTRL)                                                   \
  (red) = fmaxf((red), __int_as_float(__builtin_amdgcn_update_dpp(           \
      __float_as_int(red), __float_as_int(red), (CTRL), 0xf, 0xf, false)))

struct LdsLayout {
  float c1[RING][GROUP_ROWS][64];   // label0 prob, SoA (lane-major)
  float c3[RING][GROUP_ROWS][64];   // label1 prob
  float cb[RING][GROUP_ROWS];       // blank prob (per row, broadcast read)
  int   prod_flag[GROUPS];          // 1 when group's data is in the ring
  int   cons_done;                  // number of groups fully consumed
};

__global__ __launch_bounds__(64 * (NPROD + 1)) void ctc_alpha_kernel(
    const int*   __restrict__ y_true,   // (B, U) int32
    const float* __restrict__ y_pred,   // (B, T, C) f32 softmax probs
    float*       __restrict__ out,      // (B, 1) f32
    int B)
{
  __shared__ LdsLayout L;

  const int b = blockIdx.x;
  if (b >= B) return;
  const int tid  = threadIdx.x;
  const int wid  = tid >> 6;            // 0 = consumer, 1..NPROD = producers
  const int lane = tid & 63;
  const float* __restrict__ p  = y_pred + (size_t)b * (T_DIM * C_DIM);
  const int*   __restrict__ yb = y_true + b * U_DIM;
  const int blank = C_DIM - 1;

  // Lane l owns states 4l..4l+3 (+ state 256 as slot 4 on lane 63).
  // Odd-state labels: s=4l+1 -> u=2l ; s=4l+3 -> u=2l+1 (same map all waves).
  const int ylab0 = yb[2 * lane];
  const int ylab1 = yb[2 * lane + 1];

  // Init flags, then one block barrier before the pipeline starts.
  if (wid == 0) {
    for (int i = lane; i < GROUPS; i += 64) L.prod_flag[i] = 0;
    if (lane == 0) L.cons_done = 0;
  }
  __syncthreads();

  if (wid > 0) {
    // ---------------- producers ----------------
    for (int g = wid - 1; g < GROUPS; g += NPROD) {
      // Ring space: group g reuses the slot of group g-RING; consumer must
      // have finished it (cons_done >= g-RING+1).
      if (g >= RING) {
        while (__hip_atomic_load(&L.cons_done, __ATOMIC_ACQUIRE,
                                 __HIP_MEMORY_SCOPE_WORKGROUP) < g - (RING - 1))
          __builtin_amdgcn_s_sleep(2);
      }
      const int slot = g & (RING - 1);
      const float* rp = p + (size_t)g * GROUP_ROWS * C_DIM;

      float v1[GROUP_ROWS], v3[GROUP_ROWS];
#pragma unroll
      for (int u = 0; u < GROUP_ROWS; ++u) {
        v1[u] = rp[u * C_DIM + ylab0];
        v3[u] = rp[u * C_DIM + ylab1];
      }
      float myb = 0.0f;
      if (lane < GROUP_ROWS) myb = rp[lane * C_DIM + blank];

#pragma unroll
      for (int u = 0; u < GROUP_ROWS; ++u) {
        L.c1[slot][u][lane] = v1[u];
        L.c3[slot][u][lane] = v3[u];
      }
      if (lane < GROUP_ROWS) L.cb[slot][lane] = myb;

      // Release: all LDS data writes visible before the flag.
      __hip_atomic_store(&L.prod_flag[g], 1, __ATOMIC_RELEASE,
                         __HIP_MEMORY_SCOPE_WORKGROUP);
    }
    return;
  }

  // ---------------- consumer (wave 0): serial alpha recursion ----------------
  int yprev = blank;
  if (lane > 0) yprev = yb[2 * lane - 1];
  const float allow1 = (lane > 0 && ylab0 != blank && ylab0 != yprev) ? 1.0f : 0.0f;
  const float allow3 = (ylab1 != blank && ylab1 != ylab0)             ? 1.0f : 0.0f;

  // Virtual init: alpha_{-1}=1 on lane0 makes t=0 a uniform step.
  float a0 = (lane == 0) ? 1.0f : 0.0f;
  float a1 = 0.f, a2 = 0.f, a3 = 0.f, a4 = 0.f;
  int   e_acc = 0;

  for (int g = 0; g < GROUPS; ++g) {
    while (!__hip_atomic_load(&L.prod_flag[g], __ATOMIC_ACQUIRE,
                              __HIP_MEMORY_SCOPE_WORKGROUP))
      __builtin_amdgcn_s_sleep(1);
    const int slot = g & (RING - 1);

#pragma unroll
    for (int u = 0; u < GROUP_ROWS; ++u) {
      // Commit row t = g*16+u (bit-identical to R7: p + eps, no prescale).
      const float c1 = L.c1[slot][u][lane] + EPSF;   // stride-1: conflict-free
      const float c3 = L.c3[slot][u][lane] + EPSF;
      const float cb = L.cb[slot][u]       + EPSF;   // broadcast: free

      // Alpha update; sh3 via DPP wave_shr:1 (lane0 -> exact 0).
      float sh3 = dpp_wave_shr1(a3);
      float n0 = (a0 + sh3)                 * cb;
      float n1 = fmaf(sh3, allow1, a0 + a1) * c1;
      float n2 = (a1 + a2)                  * cb;
      float n3 = fmaf(a1,  allow3, a2 + a3) * c3;
      float n4 = (a3 + a4)                  * cb;    // state 256 (lane63)
      a0 = n0; a1 = n1; a2 = n2; a3 = n3; a4 = n4;

      // Exact power-of-2 renorm every 8th step (t%8==7): recenter max at 2^40.
      if ((u & 7) == 7) {
        float red = fmaxf(fmaxf(fmaxf(a0, a1), fmaxf(a2, a3)), a4);
        ROR_MAX(red, 0x128);                 // row_ror:8
        ROR_MAX(red, 0x124);                 // row_ror:4
        ROR_MAX(red, 0x122);                 // row_ror:2
        ROR_MAX(red, 0x121);                 // row_ror:1 -> row(16) max
        int r0 = __builtin_amdgcn_readlane(__float_as_int(red), 0);
        int r1 = __builtin_amdgcn_readlane(__float_as_int(red), 16);
        int r2 = __builtin_amdgcn_readlane(__float_as_int(red), 32);
        int r3 = __builtin_amdgcn_readlane(__float_as_int(red), 48);
        int m01 = r0 > r1 ? r0 : r1;
        int m23 = r2 > r3 ? r2 : r3;
        int rmb = m01 > m23 ? m01 : m23;     // wave max (positive f32 as int)
        int eb = (rmb >> 23) & 0xff;
        int sb = TARGET_BEXP - eb;
        if (sb > 254) sb = 254;
        float sc = __uint_as_float((unsigned)sb << 23);  // exact power of 2
        a0 *= sc; a1 *= sc; a2 *= sc; a3 *= sc; a4 *= sc;
        e_acc += 127 - sb;
      }
    }

    __hip_atomic_store(&L.cons_done, g + 1, __ATOMIC_RELEASE,
                       __HIP_MEMORY_SCOPE_WORKGROUP);
  }

  if (lane == 63) {
    float s = a3 + a4;                 // alpha[255] + alpha[256]
    s = fmaxf(s, 1e-37f);
    float ll = logf(s) + (float)e_acc * LN2F;
    out[b] = -ll;
  }
}

extern "C" void kernel_launch(void* const* d_in, const int* in_sizes, int n_in,
                              void* d_out, int out_size, void* d_ws, size_t ws_size,
                              hipStream_t stream) {
  const int*   y_true = (const int*)d_in[0];
  const float* y_pred = (const float*)d_in[1];
  float*       out    = (float*)d_out;
  const int B = in_sizes[0] / U_DIM;   // 256
  ctc_alpha_kernel<<<dim3(B), dim3(64 * (NPROD + 1)), 0, stream>>>(
      y_true, y_pred, out, B);
}